// Round 5
// baseline (73.449 us; speedup 1.0000x reference)
//
#include <hip/hip_runtime.h>

// Quanv2d: 4096 images x 196 (2x2) patches -> 4-qubit circuit -> 4 expvals.
// One thread per patch/circuit; 16-amplitude state in registers. No LDS.
//
// Exact algebraic folds:
//   per qubit: H, RY(x_q), RY(w[0,q]) -> product state, angle x_q + w[0,q]
//   CNOT chain = compile-time register permutation (0 instructions)
//   RY(w[0,4+q]) . RY(w[1,q])         -> one RY, half-angle (w[0,4+q]+w[1,q])/2
//   CNOT chain
//   final RY(w[1,4+q]) folded INTO the measurement:
//     Z_q invariant under rotations of other qubits;
//     <Z_q> after RY(phi) = cos(phi)*sum(a0^2-a1^2) - sin(phi)*2*sum(a0*a1)
//   -> ev_q = c3[q]*D_q - (2*sin(phi3_q))*C_q

constexpr float INV_SQRT2f = 0.7071067811865476f;

#define TOTAL_CIRCUITS (4096 * 196)   // 802816 = 3136 * 256

__global__ __launch_bounds__(256) void quanv_kernel(
    const float* __restrict__ x,    // (4096,1,28,28)
    const float* __restrict__ w,    // (2,8) row-major
    float* __restrict__ out)        // (4096,784)
{
    // ---- wave-uniform weight trig (recomputed by all lanes; ~40 VALU, no LDS/barrier)
    float w0[4], c2[4], s2[4], c3[4], s3d[4];
    #pragma unroll
    for (int q = 0; q < 4; ++q) {
        w0[q] = w[q];
        const float h2 = 0.5f * (w[4 + q] + w[8 + q]);   // fused mid RY half-angle
        __sincosf(h2, &s2[q], &c2[q]);
        float sf, cf;
        __sincosf(w[12 + q], &sf, &cf);                  // FULL angle for folded measurement
        c3[q]  = cf;
        s3d[q] = 2.0f * sf;
    }

    const int t = blockIdx.x * 256 + threadIdx.x;   // grid exact: 3136*256 == TOTAL_CIRCUITS
    const int b  = t / 196;
    const int p  = t - b * 196;
    const int pi = p / 14;
    const int pj = p - pi * 14;

    // angles q=0..3 = x[2i,2j], x[2i,2j+1], x[2i+1,2j], x[2i+1,2j+1]
    const float* xp = x + b * 784 + pi * 56 + pj * 2;
    const float2 r0 = *reinterpret_cast<const float2*>(xp);
    const float2 r1 = *reinterpret_cast<const float2*>(xp + 28);
    const float ang[4] = { r0.x, r0.y, r1.x, r1.y };

    // per-qubit initial 2-vectors: RY(x_q + w0q) . H . |0>
    float v0[4], v1[4];
    #pragma unroll
    for (int q = 0; q < 4; ++q) {
        float s, c;
        __sincosf(0.5f * (ang[q] + w0[q]), &s, &c);
        v0[q] = (c - s) * INV_SQRT2f;
        v1[q] = (c + s) * INV_SQRT2f;
    }

    // psi[i], i = (q0<<3)|(q1<<2)|(q2<<1)|q3  (qubit 0 = MSB per reference axis order)
    float psi[16];
    {
        float p01[4];
        p01[0] = v0[0] * v0[1]; p01[1] = v0[0] * v1[1];
        p01[2] = v1[0] * v0[1]; p01[3] = v1[0] * v1[1];
        float p012[8];
        #pragma unroll
        for (int i = 0; i < 4; ++i) {
            p012[2 * i]     = p01[i] * v0[2];
            p012[2 * i + 1] = p01[i] * v1[2];
        }
        #pragma unroll
        for (int i = 0; i < 8; ++i) {
            psi[2 * i]     = p012[i] * v0[3];
            psi[2 * i + 1] = p012[i] * v1[3];
        }
    }

#define CNOT_GATE(C, T)                                                        \
    {                                                                          \
        const int bc = 1 << (3 - (C)), bt = 1 << (3 - (T));                    \
        _Pragma("unroll")                                                      \
        for (int i = 0; i < 16; ++i)                                           \
            if ((i & bc) && !(i & bt)) {                                       \
                const float tmp = psi[i];                                      \
                psi[i] = psi[i | bt];                                          \
                psi[i | bt] = tmp;                                             \
            }                                                                  \
    }

#define RY_GATE(Q, CC, SS)                                                     \
    {                                                                          \
        const int bq = 1 << (3 - (Q));                                         \
        _Pragma("unroll")                                                      \
        for (int i = 0; i < 16; ++i)                                           \
            if (!(i & bq)) {                                                   \
                const float a0 = psi[i], a1 = psi[i | bq];                     \
                psi[i]      = (CC) * a0 - (SS) * a1;                           \
                psi[i | bq] = (SS) * a0 + (CC) * a1;                           \
            }                                                                  \
    }

    // depth-0 entangler (free)
    CNOT_GATE(0, 1); CNOT_GATE(1, 2); CNOT_GATE(2, 3);

    // fused mid RY layer
    #pragma unroll
    for (int q = 0; q < 4; ++q) RY_GATE(q, c2[q], s2[q]);

    // depth-1 entangler (free)
    CNOT_GATE(0, 1); CNOT_GATE(1, 2); CNOT_GATE(2, 3);

    // ---- measurement with final RY layer folded in ----
    float sq[16];
    #pragma unroll
    for (int i = 0; i < 16; ++i) sq[i] = psi[i] * psi[i];

    // diagonal Walsh sums D_q = sum_i sign_q(i) * sq[i], shared-partial tree (40 ops)
    float A[8], B[8];
    #pragma unroll
    for (int m = 0; m < 8; ++m) { A[m] = sq[m] + sq[m + 8]; B[m] = sq[m] - sq[m + 8]; }
    const float D0 = ((B[0] + B[1]) + (B[2] + B[3])) + ((B[4] + B[5]) + (B[6] + B[7]));
    float G[4], H[4];
    #pragma unroll
    for (int k = 0; k < 4; ++k) { G[k] = A[k] + A[k + 4]; H[k] = A[k] - A[k + 4]; }
    const float D1 = (H[0] + H[1]) + (H[2] + H[3]);
    const float D2 = (G[0] + G[1]) - (G[2] + G[3]);
    const float D3 = (G[0] + G[2]) - (G[1] + G[3]);

    // cross terms C_q = sum_{i: bit_q=0} psi[i]*psi[i|bq]
    float C0 = 0.f, C1 = 0.f, C2 = 0.f, C3 = 0.f;
    #pragma unroll
    for (int i = 0; i < 8; ++i)  C0 += psi[i] * psi[i + 8];
    #pragma unroll
    for (int i = 0; i < 16; ++i) if (!(i & 4)) C1 += psi[i] * psi[i | 4];
    #pragma unroll
    for (int i = 0; i < 16; ++i) if (!(i & 2)) C2 += psi[i] * psi[i | 2];
    #pragma unroll
    for (int i = 0; i < 16; ++i) if (!(i & 1)) C3 += psi[i] * psi[i | 1];

    float4 o;
    o.x = c3[0] * D0 - s3d[0] * C0;
    o.y = c3[1] * D1 - s3d[1] * C1;
    o.z = c3[2] * D2 - s3d[2] * C2;
    o.w = c3[3] * D3 - s3d[3] * C3;

    // out[b, p*4 + q] -> flat offset t*4 (16B aligned)
    *reinterpret_cast<float4*>(out + 4 * t) = o;
}

extern "C" void kernel_launch(void* const* d_in, const int* in_sizes, int n_in,
                              void* d_out, int out_size, void* d_ws, size_t ws_size,
                              hipStream_t stream) {
    const float* x = (const float*)d_in[0];
    const float* w = (const float*)d_in[1];
    float* out = (float*)d_out;
    (void)in_sizes; (void)n_in; (void)d_ws; (void)ws_size; (void)out_size;

    quanv_kernel<<<TOTAL_CIRCUITS / 256, 256, 0, stream>>>(x, w, out);
}